// Round 9
// baseline (2796.370 us; speedup 1.0000x reference)
//
#include <hip/hip_runtime.h>

// ForwardDecoder: 2048x2048x3 softmax-HMM forward DP.
// R21 = R20 topology (4 blocks x 8 chained compute waves + IN/OUT = 10 waves,
// 2 compute waves per SIMD) with the PRIORITY INVERSION fixed.
// R20 post-mortem: compute waves spun at prio 1 with no sleep, starving the
// prio-0 transporters co-resident on their SIMDs -> ring feed collapsed
// (fwd 2668us, one 33ms outlier; VALUBusy 0.16). R16 already proved
// co-residency itself is fine (467us, no setprio). Fixes:
//  (1) transporters run at setprio(2) (sleep when idle; never starved),
//  (2) compute: prio 0 while polling, setprio(1) ONLY inside the window
//      body (loads/steps/renorms), back to 0 before the next poll,
//  (3) s_sleep(1) inside every compute spin loop (free on the fast path).
// Body carried unchanged from R17/R18: unified compute path (rings raw; IN
// expands bf16->raw, OUT compresses raw->bf16+tags), triple-buffered
// distance-2 theta prefetch with KEEPQ pins, frexp renorms, skewed E'
// (RSTRIDE=6336, +2 pad rows), division-free exp_pre.

typedef unsigned long long ull;
typedef float f4 __attribute__((ext_vector_type(4)));

#define LANES 64
#define NDIM 2048
#define MDIM 2048
#define BANDS 4                  // blocks; 512 rows each
#define CWAVES 8                 // compute waves (stages) per block
#define NWIN 132                 // (2048 + 64) / 16
#define NBOUND (BANDS - 1)
#define SLOT_ULL 18              // 16 cols + bias0 + bias1
#define NSLOTS 129
#define BOUND_ULL (NSLOTS * SLOT_ULL)
#define THMAXI (3 * NDIM * MDIM - 4)
#define RING 16
#define RSTRIDE (48 * NWIN)      // 6336 floats per skewed E' row
#define RSF4 (RSTRIDE / 4)       // 1584 float4 per E' row

#define WGSCOPE __HIP_MEMORY_SCOPE_WORKGROUP
#define LGKM0() asm volatile("s_waitcnt lgkmcnt(0)" ::: "memory")

__device__ __forceinline__ float rf(float x) {
    return __int_as_float(__builtin_amdgcn_readfirstlane(__float_as_int(x)));
}
__device__ __forceinline__ float ex2(float x) { return __builtin_amdgcn_exp2f(x); }
__device__ __forceinline__ float lg2(float x) { return __builtin_amdgcn_logf(x); }
__device__ __forceinline__ int clampi(int x, int lo, int hi) { return x < lo ? lo : (x > hi ? hi : x); }
__device__ __forceinline__ void ld16(f4* d, const float* p) { __builtin_memcpy(d, p, 16); }
__device__ __forceinline__ void schedbar() { __builtin_amdgcn_sched_barrier(0); }

#if __has_builtin(__builtin_amdgcn_update_dpp)
__device__ __forceinline__ float shup1(float x) {
    return __int_as_float(__builtin_amdgcn_update_dpp(
        0, __float_as_int(x), 0x138 /*wave_shr:1*/, 0xf, 0xf, true));
}
#else
__device__ __forceinline__ float shup1(float x) { return __shfl_up(x, 1); }
#endif

__device__ __forceinline__ ull ald(const ull* p) {
    return __hip_atomic_load(p, __ATOMIC_RELAXED, __HIP_MEMORY_SCOPE_AGENT);
}
__device__ __forceinline__ void ast(ull* p, ull v) {
    __hip_atomic_store(p, v, __ATOMIC_RELAXED, __HIP_MEMORY_SCOPE_AGENT);
}
__device__ __forceinline__ float lo_f(ull u) { return __int_as_float((int)(unsigned)u); }
__device__ __forceinline__ float hi_f(ull u) { return __int_as_float((int)(u >> 32)); }
__device__ __forceinline__ int   hi_i(ull u) { return (int)(u >> 32); }
__device__ __forceinline__ ull   pk(float x, int tag) {
    return ((ull)(unsigned)tag << 32) | (ull)(unsigned)__float_as_int(x);
}
__device__ __forceinline__ ull pkraw(float a, float b2) {
    return ((ull)(unsigned)__float_as_int(b2) << 32) | (ull)(unsigned)__float_as_int(a);
}
__device__ __forceinline__ unsigned bf1(float x) {
    unsigned u = __float_as_uint(x);
    return (u + 0x7FFFu + ((u >> 16) & 1u)) >> 16;
}
__device__ __forceinline__ ull pk2(float m, float i, int tag) {
    return ((ull)(unsigned)tag << 32) | (ull)(bf1(m) | (bf1(i) << 16));
}
__device__ __forceinline__ float bflo(ull u) { return __uint_as_float((unsigned)u << 16); }
__device__ __forceinline__ float bfhi(ull u) { return __uint_as_float((unsigned)u & 0xFFFF0000u); }

#define THV16(T, u, c) (T[(3*(u)+(c)) >> 2][(3*(u)+(c)) & 3])

// Pin a 12-f4 tile into registers HERE.
#define KEEPQ(THQ) asm volatile("" :                                             \
    "+v"(THQ[0]), "+v"(THQ[1]), "+v"(THQ[2]),  "+v"(THQ[3]),                     \
    "+v"(THQ[4]), "+v"(THQ[5]), "+v"(THQ[6]),  "+v"(THQ[7]),                     \
    "+v"(THQ[8]), "+v"(THQ[9]), "+v"(THQ[10]), "+v"(THQ[11]))

// ---------------- PRE==1: aligned loads from skewed E' ----------------
#define THLOAD_P(THQ, wnext) {                                                   \
    const float* tp_ = theta + thRowBase + 48 * (wnext);                         \
    ld16(&THQ[0], tp_);       ld16(&THQ[1], tp_ + 4);  ld16(&THQ[2], tp_ + 8);   \
    ld16(&THQ[3], tp_ + 12);  ld16(&THQ[4], tp_ + 16); ld16(&THQ[5], tp_ + 20);  \
    ld16(&THQ[6], tp_ + 24);  ld16(&THQ[7], tp_ + 28); ld16(&THQ[8], tp_ + 32);  \
    ld16(&THQ[9], tp_ + 36);  ld16(&THQ[10], tp_ + 40); ld16(&THQ[11], tp_ + 44);\
}
// ---------------- PRE==0 fallback: clamped loads ----------------------------
#define THLOAD_C(THQ, wnext) {                                                   \
    int fidx_ = thRowBase + 3 * (16 * (wnext) - r);                              \
    ld16(&THQ[0], theta + clampi(fidx_,      0, THMAXI));                        \
    ld16(&THQ[1], theta + clampi(fidx_ + 4,  0, THMAXI));                        \
    ld16(&THQ[2], theta + clampi(fidx_ + 8,  0, THMAXI));                        \
    ld16(&THQ[3], theta + clampi(fidx_ + 12, 0, THMAXI));                        \
    ld16(&THQ[4], theta + clampi(fidx_ + 16, 0, THMAXI));                        \
    ld16(&THQ[5], theta + clampi(fidx_ + 20, 0, THMAXI));                        \
    ld16(&THQ[6], theta + clampi(fidx_ + 24, 0, THMAXI));                        \
    ld16(&THQ[7], theta + clampi(fidx_ + 28, 0, THMAXI));                        \
    ld16(&THQ[8], theta + clampi(fidx_ + 32, 0, THMAXI));                        \
    ld16(&THQ[9], theta + clampi(fidx_ + 36, 0, THMAXI));                        \
    ld16(&THQ[10], theta + clampi(fidx_ + 40, 0, THMAXI));                       \
    ld16(&THQ[11], theta + clampi(fidx_ + 44, 0, THMAXI));                       \
    if (row == NDIM - 1 && (wnext) == NWIN - 1)                                  \
        THV16(THQ, 14, 2) = theta[3 * NDIM * MDIM - 1];                          \
}
#define THLOAD(THQ, wnext)                                                       \
    if constexpr (PRE != 0) THLOAD_P(THQ, wnext) else THLOAD_C(THQ, wnext)

// producers (unified: raw into ringOut)
#define PRDF(u) { if (isP) ringOut[ori][u] = pkraw(dM, dI); }
#define PRDM(u) { if (isP && valid && w >= 3) ringOut[ori][u] = pkraw(dM, dI); }

#define STEP_F(u, X0v, D0v, X1v, D1v, CMv, CIv, PRDm) {                          \
    float nM = shup1(dM), nI = shup1(dI);                                        \
    nM = isC ? (CMv) : nM;  nI = isC ? (CIv) : nI;                               \
    float T0, T1, T2;                                                            \
    if constexpr (PRE != 0) {                                                    \
        T0 = THV16(THL, u, 0) * (X0v);                                           \
        T1 = THV16(THL, u, 1) * (X1v);                                           \
        T2 = THV16(THL, u, 2);                                                   \
    } else {                                                                     \
        T0 = ex2(fmaf(THV16(THL, u, 0), INVLN2, (D0v)));                         \
        T1 = ex2(fmaf(THV16(THL, u, 1), INVLN2, (D1v)));                         \
        T2 = ex2(THV16(THL, u, 2) * INVLN2);                                     \
    }                                                                            \
    float nv2 = T2 * fmaf(a22, v2, fmaf(v1, a21, v0 * a20));                     \
    v0 = T0 * prevM;  v1 = T1 * nI;  v2 = nv2;                                   \
    prevM = nM;                                                                  \
    dM = fmaf(v2, a02, fmaf(v1, a01, v0 * a00));                                 \
    dI = fmaf(v2, a12, fmaf(v1, a11, v0 * a10));                                 \
    PRDm(u)                                                                      \
}
#define STEP_M(u, X0v, D0v, X1v, D1v, CMv, CIv, PRDm) {                          \
    float nM = shup1(dM), nI = shup1(dI);                                        \
    nM = isC ? (CMv) : nM;  nI = isC ? (CIv) : nI;                               \
    bool valid = (unsigned)(j - 1) < (unsigned)MDIM;                             \
    float T0, T1, T2;                                                            \
    if constexpr (PRE != 0) {                                                    \
        T0 = THV16(THL, u, 0) * (X0v);                                           \
        T1 = THV16(THL, u, 1) * (X1v);                                           \
        T2 = THV16(THL, u, 2);                                                   \
    } else {                                                                     \
        T0 = ex2(fmaf(THV16(THL, u, 0), INVLN2, (D0v)));                         \
        T1 = ex2(fmaf(THV16(THL, u, 1), INVLN2, (D1v)));                         \
        T2 = ex2(THV16(THL, u, 2) * INVLN2);                                     \
    }                                                                            \
    float nv2 = T2 * fmaf(a22, v2, fmaf(v1, a21, v0 * a20));                     \
    float nv0 = T0 * prevM, nv1 = T1 * nI;                                       \
    v0 = valid ? nv0 : v0; v1 = valid ? nv1 : v1; v2 = valid ? nv2 : v2;         \
    prevM = nM;                                                                  \
    dM = fmaf(v2, a02, fmaf(v1, a01, v0 * a00));                                 \
    dI = fmaf(v2, a12, fmaf(v1, a11, v0 * a10));                                 \
    PRDm(u)                                                                      \
    j += 1;                                                                      \
}

// half 1: steps 0..7 consume carM, L[0..6]; half 2: steps 8..15 consume L[7..14]
#define GMR(k) lo_f(L[k])
#define GIR(k) hi_f(L[k])
#define STEPS_FIRST(STP, PRDm)                                                   \
    STP(0,  XP, dA, XQ, dB, carM, carI, PRDm)                                    \
    STP(1,  XQ, dB, XS, dC, GMR(0),  GIR(0),  PRDm)                              \
    STP(2,  XS, dC, XS, dC, GMR(1),  GIR(1),  PRDm)                              \
    STP(3,  XS, dC, XS, dC, GMR(2),  GIR(2),  PRDm)                              \
    STP(4,  XS, dC, XS, dC, GMR(3),  GIR(3),  PRDm)                              \
    STP(5,  XS, dC, XS, dC, GMR(4),  GIR(4),  PRDm)                              \
    STP(6,  XS, dC, XS, dC, GMR(5),  GIR(5),  PRDm)                              \
    STP(7,  XS, dC, XS, dC, GMR(6),  GIR(6),  PRDm)
#define STEPS_SECOND(STP, PRDm)                                                  \
    STP(8,  XP2, dA2, XQ2, dB2, GMR(7),  GIR(7),  PRDm)                          \
    STP(9,  XQ2, dB2, XS2, dC2, GMR(8),  GIR(8),  PRDm)                          \
    STP(10, XS2, dC2, XS2, dC2, GMR(9),  GIR(9),  PRDm)                          \
    STP(11, XS2, dC2, XS2, dC2, GMR(10), GIR(10), PRDm)                          \
    STP(12, XS2, dC2, XS2, dC2, GMR(11), GIR(11), PRDm)                          \
    STP(13, XS2, dC2, XS2, dC2, GMR(12), GIR(12), PRDm)                          \
    STP(14, XS2, dC2, XS2, dC2, GMR(13), GIR(13), PRDm)                          \
    STP(15, XS2, dC2, XS2, dC2, GMR(14), GIR(14), PRDm)

// Renorms via exponent extraction (exact pair sc = 2^-l, no lg2/rcp).
#define MIDRENORM() {                                                            \
    float mm = v0 + v1 + v2;                                                     \
    bool g = mm > 1e-33f;                                                        \
    int ei = (int)((__float_as_uint(mm) >> 23) & 0xFFu) - 127;                   \
    float l  = g ? (float)ei : (Bup - B);                                        \
    float sc = g ? __uint_as_float((unsigned)(127 - ei) << 23) : 1.0f;           \
    v0 *= sc; v1 *= sc; v2 *= sc; dM *= sc; dI *= sc;                            \
    B += l;                                                                      \
    float lup = shup1(l);                                                        \
    float dOldM = fminf(Bup - B, 100.f);                                         \
    Bup += lup;                                                                  \
    float dNewM = fminf(Bup - B, 100.f);                                         \
    float dCarM = fminf(lo_f(L[16]) - B, 100.f);                                 \
    dA2 = isC ? dCarM : dOldM;                                                   \
    dB2 = isC ? dCarM : dNewM;                                                   \
    float dLive1 = fminf(lo_f(L[17]) - B, 100.f);                                \
    dC2 = isC ? dLive1 : dNewM;                                                  \
    dNewC = dNewM;                                                               \
    if constexpr (PRE != 0) { XP2 = ex2(dA2); XQ2 = ex2(dB2); XS2 = ex2(dC2); }  \
}
#define RENORM16() {                                                             \
    float mm = v0 + v1 + v2;                                                     \
    bool g = mm > 1e-33f;                                                        \
    int ei = (int)((__float_as_uint(mm) >> 23) & 0xFFu) - 127;                   \
    float l  = g ? (float)ei : (Bup - B);                                        \
    float sc = g ? __uint_as_float((unsigned)(127 - ei) << 23) : 1.0f;           \
    v0 *= sc; v1 *= sc; v2 *= sc; dM *= sc; dI *= sc;                            \
    B += l;                                                                      \
    float lup = shup1(l);                                                        \
    float dOld = fminf(Bup - B, 100.f);                                          \
    Bup += lup;                                                                  \
    float dNew = fminf(Bup - B, 100.f);                                          \
    carM = GMR(15); carI = GIR(15);                                              \
    float dCar = fminf(lo_f(L[17]) - B, 100.f);                                  \
    dA = isC ? dCar : dOld;                                                      \
    dB = isC ? dCar : dNew;                                                      \
    dNewC = dNew;                                                                \
}
// window-top: first-half dLive from the freshly loaded entry's bias0 (L[16])
#define XSETUP() {                                                               \
    float dLive0 = fminf(lo_f(L[16]) - B, 100.f);                                \
    dC = isC ? dLive0 : dNewC;                                                   \
    if constexpr (PRE != 0) { XP = ex2(dA); XQ = ex2(dB); XS = ex2(dC); }        \
}

// spin with sleep (free on the fast path: tag usually already set)
#define LDSIN16(cond) {                                                          \
    if ((cond) && r == 0) {                                                      \
        int e_ = w + 1, ri_ = e_ & (RING - 1);                                   \
        while (__hip_atomic_load(&tagIn[ri_], __ATOMIC_ACQUIRE, WGSCOPE)         \
               != e_ + 1) { __builtin_amdgcn_s_sleep(1); }                       \
        __builtin_memcpy(&L[0], (const void*)&ringIn[ri_][0], 144);              \
        __hip_atomic_store(consIn, e_, __ATOMIC_RELAXED, WGSCOPE);               \
    }                                                                            \
}
// producer flow gate with cached monotone counter + sleep in retry
#define GATEPOLL() {                                                             \
    if (isP && w >= 19 && gateCache < w - 18) {                                  \
        for (;;) {                                                               \
            gateCache = __hip_atomic_load(gateDn, __ATOMIC_RELAXED, WGSCOPE);    \
            if (gateCache >= w - 18) break;                                      \
            __builtin_amdgcn_s_sleep(1);                                         \
        }                                                                        \
    }                                                                            \
}

// ---- unified compute window (THa=use, THb=pin, THc=load w+2) ----
// prio 0 while polling; prio 1 through the body; back to 0 at end.
#define WIN_F(THa, THb, THc) {                                                   \
    const f4* THL = (const f4*)(THa);                                            \
    LDSIN16(hasIn)                                                               \
    GATEPOLL()                                                                   \
    __builtin_amdgcn_s_setprio(1);                                               \
    THLOAD(THc, w + 2)                                                           \
    XSETUP()                                                                     \
    schedbar();                                                                  \
    int ori = (w - 3) & (RING - 1);                                              \
    STEPS_FIRST(STEP_F, PRDF)                                                    \
    if (isP) ringOut[ori][16] = pkraw(B, 0.f);                                   \
    MIDRENORM()                                                                  \
    STEPS_SECOND(STEP_F, PRDF)                                                   \
    if (isP) {                                                                   \
        ringOut[ori][17] = pkraw(B, 0.f);                                        \
        LGKM0();                                                                 \
        __hip_atomic_store(&tagOut[ori], w - 2, __ATOMIC_RELAXED, WGSCOPE);      \
    }                                                                            \
    RENORM16()                                                                   \
    KEEPQ(THb);                                                                  \
    __builtin_amdgcn_s_setprio(0);                                               \
    w++;                                                                         \
}
#define WIN_M(THa, THb, THc) {                                                   \
    const f4* THL = (const f4*)(THa);                                            \
    LDSIN16((hasIn && w <= 127))                                                 \
    GATEPOLL()                                                                   \
    __builtin_amdgcn_s_setprio(1);                                               \
    THLOAD(THc, w + 2)                                                           \
    XSETUP()                                                                     \
    schedbar();                                                                  \
    int ori = (w - 3) & (RING - 1);                                              \
    STEPS_FIRST(STEP_M, PRDM)                                                    \
    if (isP && w >= 3) ringOut[ori][16] = pkraw(B, 0.f);                         \
    MIDRENORM()                                                                  \
    STEPS_SECOND(STEP_M, PRDM)                                                   \
    if (isP && w >= 3) {                                                         \
        ringOut[ori][17] = pkraw(B, 0.f);                                        \
        if (w < NWIN - 1) {                                                      \
            LGKM0();                                                             \
            __hip_atomic_store(&tagOut[ori], w - 2, __ATOMIC_RELAXED, WGSCOPE);  \
        }                                                                        \
    }                                                                            \
    RENORM16()                                                                   \
    KEEPQ(THb);                                                                  \
    __builtin_amdgcn_s_setprio(0);                                               \
    w++;                                                                         \
}

// exp_pre: one block per row, division-free, coalesced; skewed E' output.
__global__ __launch_bounds__(256) void exp_pre(const float* __restrict__ th,
                                               float* __restrict__ E) {
    const float IV = 1.44269504088896340736f;
    const int rowi = blockIdx.x;
    const int shift = 3 * (rowi & 63);
    const float* src = th + (size_t)rowi * (3 * MDIM);
    f4* dst = (f4*)(E + (size_t)rowi * RSTRIDE);
    for (int fo4 = threadIdx.x; fo4 < RSF4; fo4 += 256) {
        int lo = fo4 * 4 - shift;
        f4 o;
        if (lo >= 0 && lo + 4 <= 3 * MDIM) {
            f4 x;
            ld16(&x, src + lo);
            o.x = ex2(x.x * IV); o.y = ex2(x.y * IV);
            o.z = ex2(x.z * IV); o.w = ex2(x.w * IV);
        } else {
            o.x = ((unsigned)lo       < (unsigned)(3 * MDIM)) ? ex2(src[lo]     * IV) : 0.f;
            o.y = ((unsigned)(lo + 1) < (unsigned)(3 * MDIM)) ? ex2(src[lo + 1] * IV) : 0.f;
            o.z = ((unsigned)(lo + 2) < (unsigned)(3 * MDIM)) ? ex2(src[lo + 2] * IV) : 0.f;
            o.w = ((unsigned)(lo + 3) < (unsigned)(3 * MDIM)) ? ex2(src[lo + 3] * IV) : 0.f;
        }
        dst[fo4] = o;
    }
}

template<int PRE>
__global__ __launch_bounds__((CWAVES + 2) * LANES, 3)
void fwd_hmm(const float* __restrict__ theta, const float* __restrict__ A,
             float* __restrict__ out, ull* __restrict__ chunks)
{
    // ringS[0] = in (IN transporter fills), ringS[CWAVES] = out (OUT drains);
    // ringS[k] for 1..CWAVES-1 are intra-block links between stages k-1 and k.
    __shared__ ull ringS[CWAVES + 1][RING][18];
    __shared__ int tagS[CWAVES + 1][RING];
    __shared__ int consS[CWAVES];   // consS[k]: wave k consumed entry counter
    __shared__ int pushedW;         // OUT transporter progress

    const int b = blockIdx.x;
    const int tid = threadIdx.x;
    const int wv = tid >> 6;
    const int r = tid & 63;
    const bool bNot0 = (b != 0);

    if (tid == 0) {
        for (int k = 0; k <= CWAVES; ++k)
            for (int i = 0; i < RING; ++i) tagS[k][i] = 0;
        for (int k = 0; k < CWAVES; ++k) consS[k] = -1;
        pushedW = 0;
    }
    __syncthreads();

    if (wv == CWAVES) {
        // ------ IN transporter (prio 2): expands bf16->raw ------
        __builtin_amdgcn_s_setprio(2);
        const int lane = r;
        const int g = lane / 18, q = lane - 18 * g;
        const bool crew = (lane < 54);
        const ull* up = chunks + (size_t)(bNot0 ? b - 1 : 0) * BOUND_ULL;
        int sIn = bNot0 ? 0 : NSLOTS;
        while (sIn < NSLOTS) {
            ull v = 0;
            int eIn = sIn + g;
            bool act = crew & (eIn < NSLOTS);
            if (act) v = ald(up + (size_t)eIn * SLOT_ULL + q);
            int cons = __hip_atomic_load(&consS[0], __ATOMIC_RELAXED, WGSCOPE);
            bool ok = false;
            if (act) {
                ok = (hi_i(v) == eIn + 1) | ((eIn == 0) & (q < 15));
                ok &= (eIn - cons) <= (RING - 1);
            }
            ull bal = __ballot(ok);
            int n = 0;
            while (n < 3 && ((bal >> (18 * n)) & 0x3FFFFull) == 0x3FFFFull) n++;
            if (n > 0) {
                ull vs = (q < 16) ? pkraw(bflo(v), bfhi(v)) : v;
                if ((g < n) & crew) ringS[0][eIn & (RING - 1)][q] = vs;
                if (lane == 0)
                    for (int k = 0; k < n; ++k)
                        __hip_atomic_store(&tagS[0][(sIn + k) & (RING - 1)],
                                           sIn + k + 1, __ATOMIC_RELEASE, WGSCOPE);
                sIn += n;
            } else __builtin_amdgcn_s_sleep(1);
        }
        return;
    }
    if (wv == CWAVES + 1) {
        // ------ OUT transporter (prio 2): compresses raw->bf16 (+tags) ------
        __builtin_amdgcn_s_setprio(2);
        const int lane = r;
        const int g = lane / 18, q = lane - 18 * g;
        const bool crew = (lane < 54);
        ull* down = chunks + (size_t)(b < NBOUND ? b : 0) * BOUND_ULL;
        int sOut = (b != BANDS - 1) ? 0 : NSLOTS;
        while (sOut < NSLOTS) {
            int eO = sOut + g;
            bool rdy = false;
            if (crew & (eO < NSLOTS))
                rdy = (__hip_atomic_load(&tagS[CWAVES][eO & (RING - 1)],
                                         __ATOMIC_ACQUIRE, WGSCOPE) == eO + 1);
            ull bal = __ballot(rdy);
            int n = 0;
            while (n < 3 && ((bal >> (18 * n)) & 0x3FFFFull) == 0x3FFFFull) n++;
            if (n > 0) {
                if ((g < n) & crew) {
                    ull v = ringS[CWAVES][eO & (RING - 1)][q];
                    ull vs = (q < 16) ? pk2(lo_f(v), hi_f(v), eO + 1)
                                      : pk(lo_f(v), eO + 1);
                    ast(down + (size_t)eO * SLOT_ULL + q, vs);
                }
                sOut += n;
                if (lane == 0)
                    __hip_atomic_store(&pushedW, sOut, __ATOMIC_RELAXED, WGSCOPE);
            } else __builtin_amdgcn_s_sleep(1);
        }
        return;
    }

    // ------------- compute waves (wv 0..CWAVES-1), 64 rows each; prio 0 -------------
    const float INVLN2 = 1.44269504088896340736f;
    const float LN2    = 0.69314718055994530942f;
    const bool isC = (r == 0);

    float a00 = rf(expf(A[0])), a01 = rf(expf(A[1])), a02 = rf(expf(A[2]));
    float a10 = rf(expf(A[3])), a11 = rf(expf(A[4])), a12 = rf(expf(A[5]));
    float a20 = rf(expf(A[6])), a21 = rf(expf(A[7])), a22 = rf(expf(A[8]));

    float v0 = 0.f, v1 = 0.f, v2 = 0.f;
    float dM = 0.f, dI = 0.f;
    float B = 0.f, Bup = 0.f;
    float dA = 0.f, dB = 0.f, dC = 0.f, dNewC = 0.f;
    float dA2 = 0.f, dB2 = 0.f, dC2 = 0.f;
    float XP = 1.f, XQ = 1.f, XS = 1.f, XP2 = 1.f, XQ2 = 1.f, XS2 = 1.f;
    float carM = 0.f, carI = 0.f;
    int gateCache = 0;
    ull L[18] = {};
    f4 TH0[12], TH1[12], TH2[12];

    // wave-role parameterization (one shared code path)
    ull (*ringIn)[18]  = ringS[wv];
    ull (*ringOut)[18] = ringS[wv + 1];
    int* tagIn   = tagS[wv];
    int* tagOut  = tagS[wv + 1];
    int* consIn  = &consS[wv];
    int* gateDn  = (wv < CWAVES - 1) ? &consS[wv + 1] : &pushedW;
    const bool hasIn = (wv > 0) || bNot0;

    const int row = b * (64 * CWAVES) + 64 * wv + r;
    const int thRowBase = row * ((PRE != 0) ? RSTRIDE : (3 * MDIM));
    const bool isP = (r == LANES - 1) && ((wv < CWAVES - 1) || (b != BANDS - 1));
    float prevM = (b == 0 && wv == 0 && r == 0) ? (a00 + a01 + a02) : 0.f;

    // prologue: issue batches 0 and 1; pin batch 0
    THLOAD(TH0, 0)
    THLOAD(TH1, 1)

    float biasD = 0.f;
    if (hasIn && r == 0) {
        while (__hip_atomic_load(&tagIn[0], __ATOMIC_ACQUIRE, WGSCOPE) != 1) {
            __builtin_amdgcn_s_sleep(1);
        }
        ull c15 = ringIn[0][15], c17 = ringIn[0][17];
        carM = lo_f(c15); carI = hi_f(c15);
        biasD = fminf(lo_f(c17), 100.f);
        __hip_atomic_store(consIn, 0, __ATOMIC_RELAXED, WGSCOPE);
    }
    dA = isC ? biasD : 0.f;
    dB = dA;
    KEEPQ(TH0);

    int w = 0;
    int j = 1 - r;
    // head M windows 0..3 (period-3 rotation: use w%3, pin (w+1)%3, load (w+2)%3)
    WIN_M(TH0, TH1, TH2)
    WIN_M(TH1, TH2, TH0)
    WIN_M(TH2, TH0, TH1)
    WIN_M(TH0, TH1, TH2)
    // F windows 4..123
    for (int it = 0; it < 40; ++it) {
        WIN_F(TH1, TH2, TH0)
        WIN_F(TH2, TH0, TH1)
        WIN_F(TH0, TH1, TH2)
    }
    // tail M windows 124..131
    j = 16 * 124 + 1 - r;
    WIN_M(TH1, TH2, TH0)
    WIN_M(TH2, TH0, TH1)
    WIN_M(TH0, TH1, TH2)
    WIN_M(TH1, TH2, TH0)
    WIN_M(TH2, TH0, TH1)
    WIN_M(TH0, TH1, TH2)
    WIN_M(TH1, TH2, TH0)
    WIN_M(TH2, TH0, TH1)

    // entry 128 atom 15 (col 2049) never produced: dummy + tag commit
    if (isP) {
        ringOut[128 & (RING - 1)][15] = pkraw(0.f, 0.f);
        LGKM0();
        __hip_atomic_store(&tagOut[128 & (RING - 1)], 129, __ATOMIC_RELAXED, WGSCOPE);
    }

    if (wv == CWAVES - 1 && b == BANDS - 1 && r == LANES - 1) {
        out[0] = (B + lg2(v0 + v1 + v2)) * LN2;   // Vt, invariant under rescales
    }
}

extern "C" void kernel_launch(void* const* d_in, const int* in_sizes, int n_in,
                              void* d_out, int out_size, void* d_ws, size_t ws_size,
                              hipStream_t stream) {
    (void)in_sizes; (void)n_in; (void)out_size;
    const float* theta = (const float*)d_in[0];
    const float* A     = (const float*)d_in[1];
    float* out = (float*)d_out;
    ull* chunks = (ull*)d_ws;    // [3 boundaries][129 slots][18 x 8B atoms]
    size_t chunkB = (size_t)NBOUND * BOUND_ULL * sizeof(ull);
    hipMemsetAsync(chunks, 0, chunkB, stream);
    size_t eoff = (chunkB + 255) & ~(size_t)255;
    // +2 padding rows so the distance-2 tail prefetch stays in bounds
    size_t need = eoff + (size_t)(NDIM + 2) * RSTRIDE * sizeof(float);
    if (ws_size >= need) {
        float* E = (float*)((char*)d_ws + eoff);
        hipLaunchKernelGGL(exp_pre, dim3(NDIM), dim3(256), 0, stream, theta, E);
        hipLaunchKernelGGL((fwd_hmm<1>), dim3(BANDS), dim3((CWAVES + 2) * LANES),
                           0, stream, E, A, out, chunks);
    } else {
        hipLaunchKernelGGL((fwd_hmm<0>), dim3(BANDS), dim3((CWAVES + 2) * LANES),
                           0, stream, theta, A, out, chunks);
    }
}

// Round 10
// 727.540 us; speedup vs baseline: 3.8436x; 3.8436x over previous
//
#include <hip/hip_runtime.h>

// ForwardDecoder: 2048x2048x3 softmax-HMM forward DP.
// R22 = R17 (best known: fwd 404us) + theta staging via global_load_lds with
// 3 LDS buffers, ISSUE-BEFORE-WAIT, counted vmcnt.
// Diagnosis: R18's VGPR=84-108 proves the compiler sinks the 12 theta loads
// to the window-end pin -> vmcnt(0) drains with zero covering work -> ~900cyc
// exposed per window (the largest piece of the 3300cyc beat). R19's asm-"=v"
// fix spilled (24 live f4 outputs). global_load_lds consumes NO VGPRs and was
// verified correct in R13/R14; R14 regressed only due to its serialized
// ds_read->lgkm(0)->issue order + 2-buffer reuse. Here:
//   window w: GLLPF(batch w+2, buf (w+2)%3)   // issue first (3rd buffer)
//             s_waitcnt vmcnt(24)             // retires batch w (2 windows old)
//             ds_read_b128 x12 (buf w%3)      // lgkm interleaved into steps
//   tail: w=130 -> vmcnt(12), w=131 -> vmcnt(0), no issue.
// Only-theta-VMEM in compute waves => counting exact. 72KB staging -> dynamic
// LDS. R20/R21's 8-wave chain abandoned (2.7ms, cause undiagnosed).
// Carried from R17: 16 bands x 128 rows, 2 compute waves + IN/OUT, unified
// body, raw rings (IN expands bf16, OUT compresses), frexp renorms, skewed E'
// (RSTRIDE=6336), division-free exp_pre, launch_bounds(256)+waves_per_eu(1,1).

typedef unsigned long long ull;
typedef float f4 __attribute__((ext_vector_type(4)));

#define LANES 64
#define NDIM 2048
#define MDIM 2048
#define BANDS 16
#define NWIN 132                 // (2048 + 64) / 16
#define NBOUND (BANDS - 1)
#define SLOT_ULL 18              // 16 cols + bias0 + bias1
#define NSLOTS 129
#define BOUND_ULL (NSLOTS * SLOT_ULL)
#define THMAXI (3 * NDIM * MDIM - 4)
#define RING 16
#define RSTRIDE (48 * NWIN)      // 6336 floats per skewed E' row
#define RSF4 (RSTRIDE / 4)       // 1584 float4 per E' row
#define THSTG_BYTES (2 * 3 * 3072 * 4)   // 2 waves x 3 bufs x 3072 floats

#define WGSCOPE __HIP_MEMORY_SCOPE_WORKGROUP
#define LGKM0() asm volatile("s_waitcnt lgkmcnt(0)" ::: "memory")

__device__ __forceinline__ float rf(float x) {
    return __int_as_float(__builtin_amdgcn_readfirstlane(__float_as_int(x)));
}
__device__ __forceinline__ float ex2(float x) { return __builtin_amdgcn_exp2f(x); }
__device__ __forceinline__ float lg2(float x) { return __builtin_amdgcn_logf(x); }
__device__ __forceinline__ int clampi(int x, int lo, int hi) { return x < lo ? lo : (x > hi ? hi : x); }
__device__ __forceinline__ void ld16(f4* d, const float* p) { __builtin_memcpy(d, p, 16); }
__device__ __forceinline__ void schedbar() { __builtin_amdgcn_sched_barrier(0); }

#if __has_builtin(__builtin_amdgcn_update_dpp)
__device__ __forceinline__ float shup1(float x) {
    return __int_as_float(__builtin_amdgcn_update_dpp(
        0, __float_as_int(x), 0x138 /*wave_shr:1*/, 0xf, 0xf, true));
}
#else
__device__ __forceinline__ float shup1(float x) { return __shfl_up(x, 1); }
#endif

__device__ __forceinline__ ull ald(const ull* p) {
    return __hip_atomic_load(p, __ATOMIC_RELAXED, __HIP_MEMORY_SCOPE_AGENT);
}
__device__ __forceinline__ void ast(ull* p, ull v) {
    __hip_atomic_store(p, v, __ATOMIC_RELAXED, __HIP_MEMORY_SCOPE_AGENT);
}
__device__ __forceinline__ float lo_f(ull u) { return __int_as_float((int)(unsigned)u); }
__device__ __forceinline__ float hi_f(ull u) { return __int_as_float((int)(u >> 32)); }
__device__ __forceinline__ int   hi_i(ull u) { return (int)(u >> 32); }
__device__ __forceinline__ ull   pk(float x, int tag) {
    return ((ull)(unsigned)tag << 32) | (ull)(unsigned)__float_as_int(x);
}
__device__ __forceinline__ ull pkraw(float a, float b2) {
    return ((ull)(unsigned)__float_as_int(b2) << 32) | (ull)(unsigned)__float_as_int(a);
}
__device__ __forceinline__ unsigned bf1(float x) {
    unsigned u = __float_as_uint(x);
    return (u + 0x7FFFu + ((u >> 16) & 1u)) >> 16;
}
__device__ __forceinline__ ull pk2(float m, float i, int tag) {
    return ((ull)(unsigned)tag << 32) | (ull)(bf1(m) | (bf1(i) << 16));
}
__device__ __forceinline__ float bflo(ull u) { return __uint_as_float((unsigned)u << 16); }
__device__ __forceinline__ float bfhi(ull u) { return __uint_as_float((unsigned)u & 0xFFFF0000u); }

#define THV16(T, u, c) (T[(3*(u)+(c)) >> 2][(3*(u)+(c)) & 3])

// Pin a 12-f4 tile (PRE==0 fallback only).
#define KEEPQ(THQ) asm volatile("" :                                             \
    "+v"(THQ[0]), "+v"(THQ[1]), "+v"(THQ[2]),  "+v"(THQ[3]),                     \
    "+v"(THQ[4]), "+v"(THQ[5]), "+v"(THQ[6]),  "+v"(THQ[7]),                     \
    "+v"(THQ[8]), "+v"(THQ[9]), "+v"(THQ[10]), "+v"(THQ[11]))

// ---------------- PRE==1: global_load_lds staging (3 buffers) ----------------
// Per-lane global src row*RSTRIDE + 48*wnext (16B-aligned, in-bounds for
// wnext<=131); LDS dest wave-uniform base, HW writes lane r at +16B*r.
typedef __attribute__((address_space(1))) const void CGV;
typedef __attribute__((address_space(3))) void LDSV;
#define GLLQ(q) __builtin_amdgcn_global_load_lds(                                \
    (CGV*)(gp_ + 4 * (q)), (LDSV*)(lb_ + 256 * (q)), 16, 0, 0);
#define GLLPF(bufi, wnext) {                                                     \
    const float* gp_ = theta + thRowBase + 48 * (wnext);                         \
    float* lb_ = thStage + (wv * 3 + (bufi)) * 3072;                             \
    GLLQ(0) GLLQ(1) GLLQ(2) GLLQ(3) GLLQ(4) GLLQ(5)                              \
    GLLQ(6) GLLQ(7) GLLQ(8) GLLQ(9) GLLQ(10) GLLQ(11)                            \
}
#define LDSRD(bufi) {                                                            \
    const float* rb_ = thStage + (wv * 3 + (bufi)) * 3072 + 4 * r;               \
    ld16(&THW[0], rb_);          ld16(&THW[1], rb_ + 256);                       \
    ld16(&THW[2], rb_ + 512);    ld16(&THW[3], rb_ + 768);                       \
    ld16(&THW[4], rb_ + 1024);   ld16(&THW[5], rb_ + 1280);                      \
    ld16(&THW[6], rb_ + 1536);   ld16(&THW[7], rb_ + 1792);                      \
    ld16(&THW[8], rb_ + 2048);   ld16(&THW[9], rb_ + 2304);                      \
    ld16(&THW[10], rb_ + 2560);  ld16(&THW[11], rb_ + 2816);                     \
}
#define VMW24() { asm volatile("s_waitcnt vmcnt(24)" ::: "memory"); schedbar(); }
#define VMW12() { asm volatile("s_waitcnt vmcnt(12)" ::: "memory"); schedbar(); }
#define VMW0()  { asm volatile("s_waitcnt vmcnt(0)"  ::: "memory"); schedbar(); }

// ---------------- PRE==0 fallback: clamped compiler loads -------------------
#define THLOAD_C(THQ, wnext) {                                                   \
    int fidx_ = thRowBase + 3 * (16 * (wnext) - r);                              \
    ld16(&THQ[0], theta + clampi(fidx_,      0, THMAXI));                        \
    ld16(&THQ[1], theta + clampi(fidx_ + 4,  0, THMAXI));                        \
    ld16(&THQ[2], theta + clampi(fidx_ + 8,  0, THMAXI));                        \
    ld16(&THQ[3], theta + clampi(fidx_ + 12, 0, THMAXI));                        \
    ld16(&THQ[4], theta + clampi(fidx_ + 16, 0, THMAXI));                        \
    ld16(&THQ[5], theta + clampi(fidx_ + 20, 0, THMAXI));                        \
    ld16(&THQ[6], theta + clampi(fidx_ + 24, 0, THMAXI));                        \
    ld16(&THQ[7], theta + clampi(fidx_ + 28, 0, THMAXI));                        \
    ld16(&THQ[8], theta + clampi(fidx_ + 32, 0, THMAXI));                        \
    ld16(&THQ[9], theta + clampi(fidx_ + 36, 0, THMAXI));                        \
    ld16(&THQ[10], theta + clampi(fidx_ + 40, 0, THMAXI));                       \
    ld16(&THQ[11], theta + clampi(fidx_ + 44, 0, THMAXI));                       \
    if (row == NDIM - 1 && (wnext) == NWIN - 1)                                  \
        THV16(THQ, 14, 2) = theta[3 * NDIM * MDIM - 1];                          \
}

// producers (unified: raw into ringOut)
#define PRDF(u) { if (isP) ringOut[ori][u] = pkraw(dM, dI); }
#define PRDM(u) { if (isP && valid && w >= 3) ringOut[ori][u] = pkraw(dM, dI); }

#define STEP_F(u, X0v, D0v, X1v, D1v, CMv, CIv, PRDm) {                          \
    float nM = shup1(dM), nI = shup1(dI);                                        \
    nM = isC ? (CMv) : nM;  nI = isC ? (CIv) : nI;                               \
    float T0, T1, T2;                                                            \
    if constexpr (PRE != 0) {                                                    \
        T0 = THV16(THL, u, 0) * (X0v);                                           \
        T1 = THV16(THL, u, 1) * (X1v);                                           \
        T2 = THV16(THL, u, 2);                                                   \
    } else {                                                                     \
        T0 = ex2(fmaf(THV16(THL, u, 0), INVLN2, (D0v)));                         \
        T1 = ex2(fmaf(THV16(THL, u, 1), INVLN2, (D1v)));                         \
        T2 = ex2(THV16(THL, u, 2) * INVLN2);                                     \
    }                                                                            \
    float nv2 = T2 * fmaf(a22, v2, fmaf(v1, a21, v0 * a20));                     \
    v0 = T0 * prevM;  v1 = T1 * nI;  v2 = nv2;                                   \
    prevM = nM;                                                                  \
    dM = fmaf(v2, a02, fmaf(v1, a01, v0 * a00));                                 \
    dI = fmaf(v2, a12, fmaf(v1, a11, v0 * a10));                                 \
    PRDm(u)                                                                      \
}
#define STEP_M(u, X0v, D0v, X1v, D1v, CMv, CIv, PRDm) {                          \
    float nM = shup1(dM), nI = shup1(dI);                                        \
    nM = isC ? (CMv) : nM;  nI = isC ? (CIv) : nI;                               \
    bool valid = (unsigned)(j - 1) < (unsigned)MDIM;                             \
    float T0, T1, T2;                                                            \
    if constexpr (PRE != 0) {                                                    \
        T0 = THV16(THL, u, 0) * (X0v);                                           \
        T1 = THV16(THL, u, 1) * (X1v);                                           \
        T2 = THV16(THL, u, 2);                                                   \
    } else {                                                                     \
        T0 = ex2(fmaf(THV16(THL, u, 0), INVLN2, (D0v)));                         \
        T1 = ex2(fmaf(THV16(THL, u, 1), INVLN2, (D1v)));                         \
        T2 = ex2(THV16(THL, u, 2) * INVLN2);                                     \
    }                                                                            \
    float nv2 = T2 * fmaf(a22, v2, fmaf(v1, a21, v0 * a20));                     \
    float nv0 = T0 * prevM, nv1 = T1 * nI;                                       \
    v0 = valid ? nv0 : v0; v1 = valid ? nv1 : v1; v2 = valid ? nv2 : v2;         \
    prevM = nM;                                                                  \
    dM = fmaf(v2, a02, fmaf(v1, a01, v0 * a00));                                 \
    dI = fmaf(v2, a12, fmaf(v1, a11, v0 * a10));                                 \
    PRDm(u)                                                                      \
    j += 1;                                                                      \
}

// half 1: steps 0..7 consume carM, L[0..6]; half 2: steps 8..15 consume L[7..14]
#define GMR(k) lo_f(L[k])
#define GIR(k) hi_f(L[k])
#define STEPS_FIRST(STP, PRDm)                                                   \
    STP(0,  XP, dA, XQ, dB, carM, carI, PRDm)                                    \
    STP(1,  XQ, dB, XS, dC, GMR(0),  GIR(0),  PRDm)                              \
    STP(2,  XS, dC, XS, dC, GMR(1),  GIR(1),  PRDm)                              \
    STP(3,  XS, dC, XS, dC, GMR(2),  GIR(2),  PRDm)                              \
    STP(4,  XS, dC, XS, dC, GMR(3),  GIR(3),  PRDm)                              \
    STP(5,  XS, dC, XS, dC, GMR(4),  GIR(4),  PRDm)                              \
    STP(6,  XS, dC, XS, dC, GMR(5),  GIR(5),  PRDm)                              \
    STP(7,  XS, dC, XS, dC, GMR(6),  GIR(6),  PRDm)
#define STEPS_SECOND(STP, PRDm)                                                  \
    STP(8,  XP2, dA2, XQ2, dB2, GMR(7),  GIR(7),  PRDm)                          \
    STP(9,  XQ2, dB2, XS2, dC2, GMR(8),  GIR(8),  PRDm)                          \
    STP(10, XS2, dC2, XS2, dC2, GMR(9),  GIR(9),  PRDm)                          \
    STP(11, XS2, dC2, XS2, dC2, GMR(10), GIR(10), PRDm)                          \
    STP(12, XS2, dC2, XS2, dC2, GMR(11), GIR(11), PRDm)                          \
    STP(13, XS2, dC2, XS2, dC2, GMR(12), GIR(12), PRDm)                          \
    STP(14, XS2, dC2, XS2, dC2, GMR(13), GIR(13), PRDm)                          \
    STP(15, XS2, dC2, XS2, dC2, GMR(14), GIR(14), PRDm)

// Renorms via exponent extraction (exact pair sc = 2^-l, no lg2/rcp).
#define MIDRENORM() {                                                            \
    float mm = v0 + v1 + v2;                                                     \
    bool g = mm > 1e-33f;                                                        \
    int ei = (int)((__float_as_uint(mm) >> 23) & 0xFFu) - 127;                   \
    float l  = g ? (float)ei : (Bup - B);                                        \
    float sc = g ? __uint_as_float((unsigned)(127 - ei) << 23) : 1.0f;           \
    v0 *= sc; v1 *= sc; v2 *= sc; dM *= sc; dI *= sc;                            \
    B += l;                                                                      \
    float lup = shup1(l);                                                        \
    float dOldM = fminf(Bup - B, 100.f);                                         \
    Bup += lup;                                                                  \
    float dNewM = fminf(Bup - B, 100.f);                                         \
    float dCarM = fminf(lo_f(L[16]) - B, 100.f);                                 \
    dA2 = isC ? dCarM : dOldM;                                                   \
    dB2 = isC ? dCarM : dNewM;                                                   \
    float dLive1 = fminf(lo_f(L[17]) - B, 100.f);                                \
    dC2 = isC ? dLive1 : dNewM;                                                  \
    dNewC = dNewM;                                                               \
    if constexpr (PRE != 0) { XP2 = ex2(dA2); XQ2 = ex2(dB2); XS2 = ex2(dC2); }  \
}
#define RENORM16() {                                                             \
    float mm = v0 + v1 + v2;                                                     \
    bool g = mm > 1e-33f;                                                        \
    int ei = (int)((__float_as_uint(mm) >> 23) & 0xFFu) - 127;                   \
    float l  = g ? (float)ei : (Bup - B);                                        \
    float sc = g ? __uint_as_float((unsigned)(127 - ei) << 23) : 1.0f;           \
    v0 *= sc; v1 *= sc; v2 *= sc; dM *= sc; dI *= sc;                            \
    B += l;                                                                      \
    float lup = shup1(l);                                                        \
    float dOld = fminf(Bup - B, 100.f);                                          \
    Bup += lup;                                                                  \
    float dNew = fminf(Bup - B, 100.f);                                          \
    carM = GMR(15); carI = GIR(15);                                              \
    float dCar = fminf(lo_f(L[17]) - B, 100.f);                                  \
    dA = isC ? dCar : dOld;                                                      \
    dB = isC ? dCar : dNew;                                                      \
    dNewC = dNew;                                                                \
}
// window-top: first-half dLive from the freshly loaded entry's bias0 (L[16])
#define XSETUP() {                                                               \
    float dLive0 = fminf(lo_f(L[16]) - B, 100.f);                                \
    dC = isC ? dLive0 : dNewC;                                                   \
    if constexpr (PRE != 0) { XP = ex2(dA); XQ = ex2(dB); XS = ex2(dC); }        \
}

#define LDSIN16(cond) {                                                          \
    if ((cond) && r == 0) {                                                      \
        int e_ = w + 1, ri_ = e_ & (RING - 1);                                   \
        while (__hip_atomic_load(&tagIn[ri_], __ATOMIC_ACQUIRE, WGSCOPE)         \
               != e_ + 1) {}                                                     \
        __builtin_memcpy(&L[0], (const void*)&ringIn[ri_][0], 144);              \
        __hip_atomic_store(consIn, e_, __ATOMIC_RELAXED, WGSCOPE);               \
    }                                                                            \
}
#define GATEPOLL() {                                                             \
    if (isP && w >= 19) {                                                        \
        while (__hip_atomic_load(gateDn, __ATOMIC_RELAXED, WGSCOPE)              \
               < w - 18) {}                                                      \
    }                                                                            \
}

// ---- unified compute window. PRE!=0: BU=use buf (w%3), BI=issue buf
// ((w+2)%3); PRE==0: THa=use, THb=pin, THc=load w+2. ----
#define WIN_F(THa, THb, THc, BU, BI) {                                           \
    const f4* THL;                                                               \
    LDSIN16(hasIn)                                                               \
    GATEPOLL()                                                                   \
    if constexpr (PRE != 0) {                                                    \
        GLLPF(BI, w + 2)                                                         \
        VMW24()                                                                  \
        LDSRD(BU)                                                                \
        THL = (const f4*)THW;                                                    \
    } else {                                                                     \
        THLOAD_C(THc, w + 2)                                                     \
        THL = (const f4*)(THa);                                                  \
    }                                                                            \
    XSETUP()                                                                     \
    schedbar();                                                                  \
    int ori = (w - 3) & (RING - 1);                                              \
    STEPS_FIRST(STEP_F, PRDF)                                                    \
    if (isP) ringOut[ori][16] = pkraw(B, 0.f);                                   \
    MIDRENORM()                                                                  \
    STEPS_SECOND(STEP_F, PRDF)                                                   \
    if (isP) {                                                                   \
        ringOut[ori][17] = pkraw(B, 0.f);                                        \
        LGKM0();                                                                 \
        __hip_atomic_store(&tagOut[ori], w - 2, __ATOMIC_RELAXED, WGSCOPE);      \
    }                                                                            \
    RENORM16()                                                                   \
    if constexpr (PRE == 0) { KEEPQ(THb); }                                      \
    w++;                                                                         \
}
#define WIN_M_BODY(THa, THb)                                                     \
    XSETUP()                                                                     \
    schedbar();                                                                  \
    int ori = (w - 3) & (RING - 1);                                              \
    STEPS_FIRST(STEP_M, PRDM)                                                    \
    if (isP && w >= 3) ringOut[ori][16] = pkraw(B, 0.f);                         \
    MIDRENORM()                                                                  \
    STEPS_SECOND(STEP_M, PRDM)                                                   \
    if (isP && w >= 3) {                                                         \
        ringOut[ori][17] = pkraw(B, 0.f);                                        \
        if (w < NWIN - 1) {                                                      \
            LGKM0();                                                             \
            __hip_atomic_store(&tagOut[ori], w - 2, __ATOMIC_RELAXED, WGSCOPE);  \
        }                                                                        \
    }                                                                            \
    RENORM16()                                                                   \
    if constexpr (PRE == 0) { KEEPQ(THb); }                                      \
    w++;
#define WIN_M(THa, THb, THc, BU, BI) {                                           \
    const f4* THL;                                                               \
    LDSIN16((hasIn && w <= 127))                                                 \
    GATEPOLL()                                                                   \
    if constexpr (PRE != 0) {                                                    \
        GLLPF(BI, w + 2)                                                         \
        VMW24()                                                                  \
        LDSRD(BU)                                                                \
        THL = (const f4*)THW;                                                    \
    } else {                                                                     \
        THLOAD_C(THc, w + 2)                                                     \
        THL = (const f4*)(THa);                                                  \
    }                                                                            \
    WIN_M_BODY(THa, THb)                                                         \
}
// tail windows 130 (vmcnt 12) and 131 (vmcnt 0): no issue.
#define WIN_M_T1(THa, THb, THc, BU) {                                            \
    const f4* THL;                                                               \
    LDSIN16((hasIn && w <= 127))                                                 \
    GATEPOLL()                                                                   \
    if constexpr (PRE != 0) {                                                    \
        VMW12()                                                                  \
        LDSRD(BU)                                                                \
        THL = (const f4*)THW;                                                    \
    } else {                                                                     \
        THLOAD_C(THc, w + 2)                                                     \
        THL = (const f4*)(THa);                                                  \
    }                                                                            \
    WIN_M_BODY(THa, THb)                                                         \
}
#define WIN_M_T2(THa, THb, THc, BU) {                                            \
    const f4* THL;                                                               \
    LDSIN16((hasIn && w <= 127))                                                 \
    GATEPOLL()                                                                   \
    if constexpr (PRE != 0) {                                                    \
        VMW0()                                                                   \
        LDSRD(BU)                                                                \
        THL = (const f4*)THW;                                                    \
    } else {                                                                     \
        THLOAD_C(THc, w + 2)                                                     \
        THL = (const f4*)(THa);                                                  \
    }                                                                            \
    WIN_M_BODY(THa, THb)                                                         \
}

// exp_pre: one block per row, division-free, coalesced; skewed E' output.
__global__ __launch_bounds__(256) void exp_pre(const float* __restrict__ th,
                                               float* __restrict__ E) {
    const float IV = 1.44269504088896340736f;
    const int rowi = blockIdx.x;
    const int shift = 3 * (rowi & 63);
    const float* src = th + (size_t)rowi * (3 * MDIM);
    f4* dst = (f4*)(E + (size_t)rowi * RSTRIDE);
    for (int fo4 = threadIdx.x; fo4 < RSF4; fo4 += 256) {
        int lo = fo4 * 4 - shift;
        f4 o;
        if (lo >= 0 && lo + 4 <= 3 * MDIM) {
            f4 x;
            ld16(&x, src + lo);
            o.x = ex2(x.x * IV); o.y = ex2(x.y * IV);
            o.z = ex2(x.z * IV); o.w = ex2(x.w * IV);
        } else {
            o.x = ((unsigned)lo       < (unsigned)(3 * MDIM)) ? ex2(src[lo]     * IV) : 0.f;
            o.y = ((unsigned)(lo + 1) < (unsigned)(3 * MDIM)) ? ex2(src[lo + 1] * IV) : 0.f;
            o.z = ((unsigned)(lo + 2) < (unsigned)(3 * MDIM)) ? ex2(src[lo + 2] * IV) : 0.f;
            o.w = ((unsigned)(lo + 3) < (unsigned)(3 * MDIM)) ? ex2(src[lo + 3] * IV) : 0.f;
        }
        dst[fo4] = o;
    }
}

template<int PRE>
__global__ __launch_bounds__(4 * LANES)
__attribute__((amdgpu_waves_per_eu(1, 1)))
void fwd_hmm(const float* __restrict__ theta, const float* __restrict__ A,
             float* __restrict__ out, ull* __restrict__ chunks)
{
    __shared__ ull inRing[RING][18];
    __shared__ ull midRing[RING][18];
    __shared__ ull outRing[RING][18];
    __shared__ int inTag[RING];
    __shared__ int midTag[RING];
    __shared__ int outTag[RING];
    __shared__ int consW;
    __shared__ int midConsW;
    __shared__ int pushedW;
    extern __shared__ float thStage[];   // PRE==1: [2 waves][3 bufs][3072 floats]

    const int b = blockIdx.x;
    const int tid = threadIdx.x;
    const int wv = tid >> 6;
    const int r = tid & 63;
    const bool bNot0 = (b != 0);

    if (tid == 0) {
        for (int i = 0; i < RING; ++i) { inTag[i] = 0; midTag[i] = 0; outTag[i] = 0; }
        consW = -1; midConsW = -1; pushedW = 0;
    }
    __syncthreads();

    if (wv == 2) {
        // ------ IN transporter: 3 slot-groups x 18 atoms; expands bf16->raw ------
        const int lane = r;
        const int g = lane / 18, q = lane - 18 * g;
        const bool crew = (lane < 54);
        const ull* up = chunks + (size_t)(bNot0 ? b - 1 : 0) * BOUND_ULL;
        int sIn = bNot0 ? 0 : NSLOTS;
        while (sIn < NSLOTS) {
            ull v = 0;
            int eIn = sIn + g;
            bool act = crew & (eIn < NSLOTS);
            if (act) v = ald(up + (size_t)eIn * SLOT_ULL + q);
            int cons = __hip_atomic_load(&consW, __ATOMIC_RELAXED, WGSCOPE);
            bool ok = false;
            if (act) {
                ok = (hi_i(v) == eIn + 1) | ((eIn == 0) & (q < 15));
                ok &= (eIn - cons) <= (RING - 1);
            }
            ull bal = __ballot(ok);
            int n = 0;
            while (n < 3 && ((bal >> (18 * n)) & 0x3FFFFull) == 0x3FFFFull) n++;
            if (n > 0) {
                ull vs = (q < 16) ? pkraw(bflo(v), bfhi(v)) : v;
                if ((g < n) & crew) inRing[eIn & (RING - 1)][q] = vs;
                if (lane == 0)
                    for (int k = 0; k < n; ++k)
                        __hip_atomic_store(&inTag[(sIn + k) & (RING - 1)],
                                           sIn + k + 1, __ATOMIC_RELEASE, WGSCOPE);
                sIn += n;
            } else __builtin_amdgcn_s_sleep(1);
        }
        return;
    }
    if (wv == 3) {
        // ------ OUT transporter: compresses raw->bf16 (+tags) on egress ------
        const int lane = r;
        const int g = lane / 18, q = lane - 18 * g;
        const bool crew = (lane < 54);
        ull* down = chunks + (size_t)(b < NBOUND ? b : 0) * BOUND_ULL;
        int sOut = (b != BANDS - 1) ? 0 : NSLOTS;
        while (sOut < NSLOTS) {
            int eO = sOut + g;
            bool rdy = false;
            if (crew & (eO < NSLOTS))
                rdy = (__hip_atomic_load(&outTag[eO & (RING - 1)],
                                         __ATOMIC_ACQUIRE, WGSCOPE) == eO + 1);
            ull bal = __ballot(rdy);
            int n = 0;
            while (n < 3 && ((bal >> (18 * n)) & 0x3FFFFull) == 0x3FFFFull) n++;
            if (n > 0) {
                if ((g < n) & crew) {
                    ull v = outRing[eO & (RING - 1)][q];
                    ull vs = (q < 16) ? pk2(lo_f(v), hi_f(v), eO + 1)
                                      : pk(lo_f(v), eO + 1);
                    ast(down + (size_t)eO * SLOT_ULL + q, vs);
                }
                sOut += n;
                if (lane == 0)
                    __hip_atomic_store(&pushedW, sOut, __ATOMIC_RELAXED, WGSCOPE);
            } else __builtin_amdgcn_s_sleep(1);
        }
        return;
    }

    // ---------------- unified compute waves (wv 0,1), 64 rows each ----------------
    const float INVLN2 = 1.44269504088896340736f;
    const float LN2    = 0.69314718055994530942f;
    const bool isC = (r == 0);

    float a00 = rf(expf(A[0])), a01 = rf(expf(A[1])), a02 = rf(expf(A[2]));
    float a10 = rf(expf(A[3])), a11 = rf(expf(A[4])), a12 = rf(expf(A[5]));
    float a20 = rf(expf(A[6])), a21 = rf(expf(A[7])), a22 = rf(expf(A[8]));

    float v0 = 0.f, v1 = 0.f, v2 = 0.f;
    float dM = 0.f, dI = 0.f;
    float B = 0.f, Bup = 0.f;
    float dA = 0.f, dB = 0.f, dC = 0.f, dNewC = 0.f;
    float dA2 = 0.f, dB2 = 0.f, dC2 = 0.f;
    float XP = 1.f, XQ = 1.f, XS = 1.f, XP2 = 1.f, XQ2 = 1.f, XS2 = 1.f;
    float carM = 0.f, carI = 0.f;
    ull L[18] = {};
    f4 TH0[12], TH1[12], TH2[12], THW[12];

    // wave-role parameterization (one shared code path)
    ull (*ringIn)[18]  = (wv == 0) ? inRing  : midRing;
    ull (*ringOut)[18] = (wv == 0) ? midRing : outRing;
    int* tagIn   = (wv == 0) ? inTag  : midTag;
    int* tagOut  = (wv == 0) ? midTag : outTag;
    int* consIn  = (wv == 0) ? &consW    : &midConsW;
    int* gateDn  = (wv == 0) ? &midConsW : &pushedW;
    const bool hasIn = (wv == 1) || bNot0;

    const int row = b * 128 + 64 * wv + r;
    const int thRowBase = row * ((PRE != 0) ? RSTRIDE : (3 * MDIM));
    const bool isP = (r == LANES - 1) && ((wv == 0) || (b != BANDS - 1));
    float prevM = (b == 0 && wv == 0 && r == 0) ? (a00 + a01 + a02) : 0.f;

    // prologue: issue batches 0 and 1
    if constexpr (PRE != 0) {
        GLLPF(0, 0)
        GLLPF(1, 1)
    } else {
        THLOAD_C(TH0, 0)
        THLOAD_C(TH1, 1)
    }

    float biasD = 0.f;
    if (hasIn && r == 0) {
        while (__hip_atomic_load(&tagIn[0], __ATOMIC_ACQUIRE, WGSCOPE) != 1) {}
        ull c15 = ringIn[0][15], c17 = ringIn[0][17];
        carM = lo_f(c15); carI = hi_f(c15);
        biasD = fminf(lo_f(c17), 100.f);
        __hip_atomic_store(consIn, 0, __ATOMIC_RELAXED, WGSCOPE);
    }
    dA = isC ? biasD : 0.f;
    dB = dA;
    if constexpr (PRE == 0) { KEEPQ(TH0); }

    int w = 0;
    int j = 1 - r;
    // head M windows 0..3 (BU = w%3, BI = (w+2)%3)
    WIN_M(TH0, TH1, TH2, 0, 2)
    WIN_M(TH1, TH2, TH0, 1, 0)
    WIN_M(TH2, TH0, TH1, 2, 1)
    WIN_M(TH0, TH1, TH2, 0, 2)
    // F windows 4..123 (40 x 3; w=4 -> BU=1)
    for (int it = 0; it < 40; ++it) {
        WIN_F(TH1, TH2, TH0, 1, 0)
        WIN_F(TH2, TH0, TH1, 2, 1)
        WIN_F(TH0, TH1, TH2, 0, 2)
    }
    // tail M windows 124..131 (124 -> BU=1); 130/131: no issue, counted drain
    j = 16 * 124 + 1 - r;
    WIN_M(TH1, TH2, TH0, 1, 0)
    WIN_M(TH2, TH0, TH1, 2, 1)
    WIN_M(TH0, TH1, TH2, 0, 2)
    WIN_M(TH1, TH2, TH0, 1, 0)
    WIN_M(TH2, TH0, TH1, 2, 1)
    WIN_M(TH0, TH1, TH2, 0, 2)
    WIN_M_T1(TH1, TH2, TH0, 1)
    WIN_M_T2(TH2, TH0, TH1, 2)

    // entry 128 atom 15 (col 2049) never produced: dummy + tag commit
    if (isP) {
        ringOut[128 & (RING - 1)][15] = pkraw(0.f, 0.f);
        LGKM0();
        __hip_atomic_store(&tagOut[128 & (RING - 1)], 129, __ATOMIC_RELAXED, WGSCOPE);
    }

    if (wv == 1 && b == BANDS - 1 && r == LANES - 1) {
        out[0] = (B + lg2(v0 + v1 + v2)) * LN2;   // Vt, invariant under rescales
    }
}

extern "C" void kernel_launch(void* const* d_in, const int* in_sizes, int n_in,
                              void* d_out, int out_size, void* d_ws, size_t ws_size,
                              hipStream_t stream) {
    (void)in_sizes; (void)n_in; (void)out_size;
    const float* theta = (const float*)d_in[0];
    const float* A     = (const float*)d_in[1];
    float* out = (float*)d_out;
    ull* chunks = (ull*)d_ws;    // [15 boundaries][129 slots][18 x 8B atoms]
    size_t chunkB = (size_t)NBOUND * BOUND_ULL * sizeof(ull);
    hipMemsetAsync(chunks, 0, chunkB, stream);
    size_t eoff = (chunkB + 255) & ~(size_t)255;
    // +2 padding rows (PRE==1 staging stays within RSTRIDE; pad is belt&braces)
    size_t need = eoff + (size_t)(NDIM + 2) * RSTRIDE * sizeof(float);
    if (ws_size >= need) {
        float* E = (float*)((char*)d_ws + eoff);
        hipLaunchKernelGGL(exp_pre, dim3(NDIM), dim3(256), 0, stream, theta, E);
        hipLaunchKernelGGL((fwd_hmm<1>), dim3(BANDS), dim3(4 * LANES),
                           THSTG_BYTES, stream, E, A, out, chunks);
    } else {
        hipLaunchKernelGGL((fwd_hmm<0>), dim3(BANDS), dim3(4 * LANES), 0, stream,
                           theta, A, out, chunks);
    }
}

// Round 11
// 469.937 us; speedup vs baseline: 5.9505x; 1.5482x over previous
//
#include <hip/hip_runtime.h>

// ForwardDecoder: 2048x2048x3 softmax-HMM forward DP.
// FINAL (= R19, best timed total 470.7us; baseline was 559-561us, -16%).
// Session summary:
//  - R17's bundle is the core win (unified compute body for both waves;
//    all rings raw f32 with IN-transporter bf16->raw expand and OUT
//    raw->bf16 compress; renorms via exponent-extract bit ops instead of
//    lg2/rcp): 554 -> 476us.
//  - R19's micro-cleanups (cached monotone flow-gate, 144B memcpy ring
//    copy, division-free block-per-row exp_pre, inline-asm theta loads):
//    476 -> 470.7us.
//  - Falsified as the residual ~2500cyc/window stall: theta VMEM latency
//    (4 independent schedules: R13/14 LDS-serial, R15 pinned regs, R19
//    asm issue-early, R22 LDS counted-vmcnt - the last PROVED decoupling
//    theta doesn't help and LDS staging costs +290cyc/window in bank
//    conflicts), transport medium (R16), register budget (R15/18), I$
//    footprint (R17), renorm trans-ops (R17), TLP chaining (R20/21 -
//    8-wave chain pathological for undiagnosed reasons).
// Structure: 16 bands x 128 rows; per block 2 compute waves (64 rows each,
// anti-diagonal wavefront, 16-col windows, mid-window renorm cadence) +
// IN/OUT transporter waves bridging bands through global 18-atom slots.

typedef unsigned long long ull;
typedef float f4 __attribute__((ext_vector_type(4)));

#define LANES 64
#define NDIM 2048
#define MDIM 2048
#define BANDS 16
#define NWIN 132                 // (2048 + 64) / 16
#define NBOUND (BANDS - 1)
#define SLOT_ULL 18              // 16 cols + bias0 + bias1
#define NSLOTS 129
#define BOUND_ULL (NSLOTS * SLOT_ULL)
#define THMAXI (3 * NDIM * MDIM - 4)
#define RING 16
#define RSTRIDE (48 * NWIN)      // 6336 floats per skewed E' row
#define RSF4 (RSTRIDE / 4)       // 1584 float4 per E' row

#define WGSCOPE __HIP_MEMORY_SCOPE_WORKGROUP
#define LGKM0() asm volatile("s_waitcnt lgkmcnt(0)" ::: "memory")

__device__ __forceinline__ float rf(float x) {
    return __int_as_float(__builtin_amdgcn_readfirstlane(__float_as_int(x)));
}
__device__ __forceinline__ float ex2(float x) { return __builtin_amdgcn_exp2f(x); }
__device__ __forceinline__ float lg2(float x) { return __builtin_amdgcn_logf(x); }
__device__ __forceinline__ int clampi(int x, int lo, int hi) { return x < lo ? lo : (x > hi ? hi : x); }
__device__ __forceinline__ void ld16(f4* d, const float* p) { __builtin_memcpy(d, p, 16); }
__device__ __forceinline__ void schedbar() { __builtin_amdgcn_sched_barrier(0); }

#if __has_builtin(__builtin_amdgcn_update_dpp)
__device__ __forceinline__ float shup1(float x) {
    return __int_as_float(__builtin_amdgcn_update_dpp(
        0, __float_as_int(x), 0x138 /*wave_shr:1*/, 0xf, 0xf, true));
}
#else
__device__ __forceinline__ float shup1(float x) { return __shfl_up(x, 1); }
#endif

__device__ __forceinline__ ull ald(const ull* p) {
    return __hip_atomic_load(p, __ATOMIC_RELAXED, __HIP_MEMORY_SCOPE_AGENT);
}
__device__ __forceinline__ void ast(ull* p, ull v) {
    __hip_atomic_store(p, v, __ATOMIC_RELAXED, __HIP_MEMORY_SCOPE_AGENT);
}
__device__ __forceinline__ float lo_f(ull u) { return __int_as_float((int)(unsigned)u); }
__device__ __forceinline__ float hi_f(ull u) { return __int_as_float((int)(u >> 32)); }
__device__ __forceinline__ int   hi_i(ull u) { return (int)(u >> 32); }
__device__ __forceinline__ ull   pk(float x, int tag) {
    return ((ull)(unsigned)tag << 32) | (ull)(unsigned)__float_as_int(x);
}
__device__ __forceinline__ ull pkraw(float a, float b2) {
    return ((ull)(unsigned)__float_as_int(b2) << 32) | (ull)(unsigned)__float_as_int(a);
}
__device__ __forceinline__ unsigned bf1(float x) {
    unsigned u = __float_as_uint(x);
    return (u + 0x7FFFu + ((u >> 16) & 1u)) >> 16;
}
__device__ __forceinline__ ull pk2(float m, float i, int tag) {
    return ((ull)(unsigned)tag << 32) | (ull)(bf1(m) | (bf1(i) << 16));
}
__device__ __forceinline__ float bflo(ull u) { return __uint_as_float((unsigned)u << 16); }
__device__ __forceinline__ float bfhi(ull u) { return __uint_as_float((unsigned)u & 0xFFFF0000u); }

#define THV16(T, u, c) (T[(3*(u)+(c)) >> 2][(3*(u)+(c)) & 3])

// Pin a 12-f4 tile (PRE==0 fallback only).
#define KEEPQ(THQ) asm volatile("" :                                             \
    "+v"(THQ[0]), "+v"(THQ[1]), "+v"(THQ[2]),  "+v"(THQ[3]),                     \
    "+v"(THQ[4]), "+v"(THQ[5]), "+v"(THQ[6]),  "+v"(THQ[7]),                     \
    "+v"(THQ[8]), "+v"(THQ[9]), "+v"(THQ[10]), "+v"(THQ[11]))

// ---------------- PRE==1: inline-asm async loads from skewed E' -------------
// One 64-bit address + 12 offset-immediate dwordx4 loads. asm volatile keeps
// issue order; the matching s_waitcnt vmcnt(0) is at the NEXT window top.
#define GLD(d, p, o) asm volatile(                                               \
    "global_load_dwordx4 %0, %1, off offset:" #o : "=v"(d) : "v"(p));
#define ISSUE_P(THQ, wnext) {                                                    \
    const float* tp_ = theta + thRowBase + 48 * (wnext);                         \
    GLD(THQ[0],  tp_, 0)   GLD(THQ[1],  tp_, 16)  GLD(THQ[2],  tp_, 32)         \
    GLD(THQ[3],  tp_, 48)  GLD(THQ[4],  tp_, 64)  GLD(THQ[5],  tp_, 80)         \
    GLD(THQ[6],  tp_, 96)  GLD(THQ[7],  tp_, 112) GLD(THQ[8],  tp_, 128)        \
    GLD(THQ[9],  tp_, 144) GLD(THQ[10], tp_, 160) GLD(THQ[11], tp_, 176)        \
}
// retire the previous batch; fence compiler motion across the wait
#define VMWAIT() {                                                               \
    if constexpr (PRE != 0) {                                                    \
        asm volatile("s_waitcnt vmcnt(0)" ::: "memory");                         \
        schedbar();                                                              \
    }                                                                            \
}
// ---------------- PRE==0 fallback: clamped compiler loads -------------------
#define THLOAD_C(THQ, wnext) {                                                   \
    int fidx_ = thRowBase + 3 * (16 * (wnext) - r);                              \
    ld16(&THQ[0], theta + clampi(fidx_,      0, THMAXI));                        \
    ld16(&THQ[1], theta + clampi(fidx_ + 4,  0, THMAXI));                        \
    ld16(&THQ[2], theta + clampi(fidx_ + 8,  0, THMAXI));                        \
    ld16(&THQ[3], theta + clampi(fidx_ + 12, 0, THMAXI));                        \
    ld16(&THQ[4], theta + clampi(fidx_ + 16, 0, THMAXI));                        \
    ld16(&THQ[5], theta + clampi(fidx_ + 20, 0, THMAXI));                        \
    ld16(&THQ[6], theta + clampi(fidx_ + 24, 0, THMAXI));                        \
    ld16(&THQ[7], theta + clampi(fidx_ + 28, 0, THMAXI));                        \
    ld16(&THQ[8], theta + clampi(fidx_ + 32, 0, THMAXI));                        \
    ld16(&THQ[9], theta + clampi(fidx_ + 36, 0, THMAXI));                        \
    ld16(&THQ[10], theta + clampi(fidx_ + 40, 0, THMAXI));                       \
    ld16(&THQ[11], theta + clampi(fidx_ + 44, 0, THMAXI));                       \
    if (row == NDIM - 1 && (wnext) == NWIN - 1)                                  \
        THV16(THQ, 14, 2) = theta[3 * NDIM * MDIM - 1];                          \
}

// producers (unified: raw into ringOut)
#define PRDF(u) { if (isP) ringOut[ori][u] = pkraw(dM, dI); }
#define PRDM(u) { if (isP && valid && w >= 3) ringOut[ori][u] = pkraw(dM, dI); }

#define STEP_F(u, X0v, D0v, X1v, D1v, CMv, CIv, PRDm) {                          \
    float nM = shup1(dM), nI = shup1(dI);                                        \
    nM = isC ? (CMv) : nM;  nI = isC ? (CIv) : nI;                               \
    float T0, T1, T2;                                                            \
    if constexpr (PRE != 0) {                                                    \
        T0 = THV16(THL, u, 0) * (X0v);                                           \
        T1 = THV16(THL, u, 1) * (X1v);                                           \
        T2 = THV16(THL, u, 2);                                                   \
    } else {                                                                     \
        T0 = ex2(fmaf(THV16(THL, u, 0), INVLN2, (D0v)));                         \
        T1 = ex2(fmaf(THV16(THL, u, 1), INVLN2, (D1v)));                         \
        T2 = ex2(THV16(THL, u, 2) * INVLN2);                                     \
    }                                                                            \
    float nv2 = T2 * fmaf(a22, v2, fmaf(v1, a21, v0 * a20));                     \
    v0 = T0 * prevM;  v1 = T1 * nI;  v2 = nv2;                                   \
    prevM = nM;                                                                  \
    dM = fmaf(v2, a02, fmaf(v1, a01, v0 * a00));                                 \
    dI = fmaf(v2, a12, fmaf(v1, a11, v0 * a10));                                 \
    PRDm(u)                                                                      \
}
#define STEP_M(u, X0v, D0v, X1v, D1v, CMv, CIv, PRDm) {                          \
    float nM = shup1(dM), nI = shup1(dI);                                        \
    nM = isC ? (CMv) : nM;  nI = isC ? (CIv) : nI;                               \
    bool valid = (unsigned)(j - 1) < (unsigned)MDIM;                             \
    float T0, T1, T2;                                                            \
    if constexpr (PRE != 0) {                                                    \
        T0 = THV16(THL, u, 0) * (X0v);                                           \
        T1 = THV16(THL, u, 1) * (X1v);                                           \
        T2 = THV16(THL, u, 2);                                                   \
    } else {                                                                     \
        T0 = ex2(fmaf(THV16(THL, u, 0), INVLN2, (D0v)));                         \
        T1 = ex2(fmaf(THV16(THL, u, 1), INVLN2, (D1v)));                         \
        T2 = ex2(THV16(THL, u, 2) * INVLN2);                                     \
    }                                                                            \
    float nv2 = T2 * fmaf(a22, v2, fmaf(v1, a21, v0 * a20));                     \
    float nv0 = T0 * prevM, nv1 = T1 * nI;                                       \
    v0 = valid ? nv0 : v0; v1 = valid ? nv1 : v1; v2 = valid ? nv2 : v2;         \
    prevM = nM;                                                                  \
    dM = fmaf(v2, a02, fmaf(v1, a01, v0 * a00));                                 \
    dI = fmaf(v2, a12, fmaf(v1, a11, v0 * a10));                                 \
    PRDm(u)                                                                      \
    j += 1;                                                                      \
}

// half 1: steps 0..7 consume carM, L[0..6]; half 2: steps 8..15 consume L[7..14]
#define GMR(k) lo_f(L[k])
#define GIR(k) hi_f(L[k])
#define STEPS_FIRST(STP, PRDm)                                                   \
    STP(0,  XP, dA, XQ, dB, carM, carI, PRDm)                                    \
    STP(1,  XQ, dB, XS, dC, GMR(0),  GIR(0),  PRDm)                              \
    STP(2,  XS, dC, XS, dC, GMR(1),  GIR(1),  PRDm)                              \
    STP(3,  XS, dC, XS, dC, GMR(2),  GIR(2),  PRDm)                              \
    STP(4,  XS, dC, XS, dC, GMR(3),  GIR(3),  PRDm)                              \
    STP(5,  XS, dC, XS, dC, GMR(4),  GIR(4),  PRDm)                              \
    STP(6,  XS, dC, XS, dC, GMR(5),  GIR(5),  PRDm)                              \
    STP(7,  XS, dC, XS, dC, GMR(6),  GIR(6),  PRDm)
#define STEPS_SECOND(STP, PRDm)                                                  \
    STP(8,  XP2, dA2, XQ2, dB2, GMR(7),  GIR(7),  PRDm)                          \
    STP(9,  XQ2, dB2, XS2, dC2, GMR(8),  GIR(8),  PRDm)                          \
    STP(10, XS2, dC2, XS2, dC2, GMR(9),  GIR(9),  PRDm)                          \
    STP(11, XS2, dC2, XS2, dC2, GMR(10), GIR(10), PRDm)                          \
    STP(12, XS2, dC2, XS2, dC2, GMR(11), GIR(11), PRDm)                          \
    STP(13, XS2, dC2, XS2, dC2, GMR(12), GIR(12), PRDm)                          \
    STP(14, XS2, dC2, XS2, dC2, GMR(13), GIR(13), PRDm)                          \
    STP(15, XS2, dC2, XS2, dC2, GMR(14), GIR(14), PRDm)

// Renorms via exponent extraction: e = exponent(mm), sc = 2^-e (bit-built),
// l = (float)e — exactly consistent pair (sc = 2^-l), no lg2/rcp trans ops.
#define MIDRENORM() {                                                            \
    float mm = v0 + v1 + v2;                                                     \
    bool g = mm > 1e-33f;                                                        \
    int ei = (int)((__float_as_uint(mm) >> 23) & 0xFFu) - 127;                   \
    float l  = g ? (float)ei : (Bup - B);                                        \
    float sc = g ? __uint_as_float((unsigned)(127 - ei) << 23) : 1.0f;           \
    v0 *= sc; v1 *= sc; v2 *= sc; dM *= sc; dI *= sc;                            \
    B += l;                                                                      \
    float lup = shup1(l);                                                        \
    float dOldM = fminf(Bup - B, 100.f);                                         \
    Bup += lup;                                                                  \
    float dNewM = fminf(Bup - B, 100.f);                                         \
    float dCarM = fminf(lo_f(L[16]) - B, 100.f);                                 \
    dA2 = isC ? dCarM : dOldM;                                                   \
    dB2 = isC ? dCarM : dNewM;                                                   \
    float dLive1 = fminf(lo_f(L[17]) - B, 100.f);                                \
    dC2 = isC ? dLive1 : dNewM;                                                  \
    dNewC = dNewM;                                                               \
    if constexpr (PRE != 0) { XP2 = ex2(dA2); XQ2 = ex2(dB2); XS2 = ex2(dC2); }  \
}
#define RENORM16() {                                                             \
    float mm = v0 + v1 + v2;                                                     \
    bool g = mm > 1e-33f;                                                        \
    int ei = (int)((__float_as_uint(mm) >> 23) & 0xFFu) - 127;                   \
    float l  = g ? (float)ei : (Bup - B);                                        \
    float sc = g ? __uint_as_float((unsigned)(127 - ei) << 23) : 1.0f;           \
    v0 *= sc; v1 *= sc; v2 *= sc; dM *= sc; dI *= sc;                            \
    B += l;                                                                      \
    float lup = shup1(l);                                                        \
    float dOld = fminf(Bup - B, 100.f);                                          \
    Bup += lup;                                                                  \
    float dNew = fminf(Bup - B, 100.f);                                          \
    carM = GMR(15); carI = GIR(15);                                              \
    float dCar = fminf(lo_f(L[17]) - B, 100.f);                                  \
    dA = isC ? dCar : dOld;                                                      \
    dB = isC ? dCar : dNew;                                                      \
    dNewC = dNew;                                                                \
}
// window-top: first-half dLive from the freshly loaded entry's bias0 (L[16])
#define XSETUP() {                                                               \
    float dLive0 = fminf(lo_f(L[16]) - B, 100.f);                                \
    dC = isC ? dLive0 : dNewC;                                                   \
    if constexpr (PRE != 0) { XP = ex2(dA); XQ = ex2(dB); XS = ex2(dC); }        \
}

#define LDSIN16(cond) {                                                          \
    if ((cond) && r == 0) {                                                      \
        int e_ = w + 1, ri_ = e_ & (RING - 1);                                   \
        while (__hip_atomic_load(&tagIn[ri_], __ATOMIC_ACQUIRE, WGSCOPE)         \
               != e_ + 1) {}                                                     \
        __builtin_memcpy(&L[0], (const void*)&ringIn[ri_][0], 144);              \
        __hip_atomic_store(consIn, e_, __ATOMIC_RELAXED, WGSCOPE);               \
    }                                                                            \
}
// producer flow gate with cached monotone counter (LDS poll only when needed)
#define GATEPOLL() {                                                             \
    if (isP && w >= 19 && gateCache < w - 18) {                                  \
        do {                                                                     \
            gateCache = __hip_atomic_load(gateDn, __ATOMIC_RELAXED, WGSCOPE);    \
        } while (gateCache < w - 18);                                            \
    }                                                                            \
}

// ---- unified compute window (both waves; THa = use, THb = issue w+1) ----
#define WIN_F(THa, THb) {                                                        \
    const f4* THL = (const f4*)(THa);                                            \
    LDSIN16(hasIn)                                                               \
    GATEPOLL()                                                                   \
    VMWAIT()                                                                     \
    if constexpr (PRE != 0) { ISSUE_P(THb, w + 1) } else { THLOAD_C(THb, w + 1) }\
    XSETUP()                                                                     \
    schedbar();                                                                  \
    int ori = (w - 3) & (RING - 1);                                              \
    STEPS_FIRST(STEP_F, PRDF)                                                    \
    if (isP) ringOut[ori][16] = pkraw(B, 0.f);                                   \
    MIDRENORM()                                                                  \
    STEPS_SECOND(STEP_F, PRDF)                                                   \
    if (isP) {                                                                   \
        ringOut[ori][17] = pkraw(B, 0.f);                                        \
        LGKM0();                                                                 \
        __hip_atomic_store(&tagOut[ori], w - 2, __ATOMIC_RELAXED, WGSCOPE);      \
    }                                                                            \
    RENORM16()                                                                   \
    if constexpr (PRE == 0) { KEEPQ(THb); }                                      \
    w++;                                                                         \
}
#define WIN_M(THa, THb) {                                                        \
    const f4* THL = (const f4*)(THa);                                            \
    LDSIN16((hasIn && w <= 127))                                                 \
    GATEPOLL()                                                                   \
    VMWAIT()                                                                     \
    if constexpr (PRE != 0) { ISSUE_P(THb, w + 1) } else { THLOAD_C(THb, w + 1) }\
    XSETUP()                                                                     \
    schedbar();                                                                  \
    int ori = (w - 3) & (RING - 1);                                              \
    int tg = w - 2; (void)tg;                                                    \
    STEPS_FIRST(STEP_M, PRDM)                                                    \
    if (isP && w >= 3) ringOut[ori][16] = pkraw(B, 0.f);                         \
    MIDRENORM()                                                                  \
    STEPS_SECOND(STEP_M, PRDM)                                                   \
    if (isP && w >= 3) {                                                         \
        ringOut[ori][17] = pkraw(B, 0.f);                                        \
        if (w < NWIN - 1) {                                                      \
            LGKM0();                                                             \
            __hip_atomic_store(&tagOut[ori], w - 2, __ATOMIC_RELAXED, WGSCOPE);  \
        }                                                                        \
    }                                                                            \
    RENORM16()                                                                   \
    if constexpr (PRE == 0) { KEEPQ(THb); }                                      \
    w++;                                                                         \
}

// exp_pre v2: one block per row, division-free, coalesced.
// Writes skewed E' = 2^(theta/ln2): row stride RSTRIDE, row data shifted
// right by 3*(row%64), zero padding.
__global__ __launch_bounds__(256) void exp_pre(const float* __restrict__ th,
                                               float* __restrict__ E) {
    const float IV = 1.44269504088896340736f;
    const int rowi = blockIdx.x;
    const int shift = 3 * (rowi & 63);
    const float* src = th + (size_t)rowi * (3 * MDIM);
    f4* dst = (f4*)(E + (size_t)rowi * RSTRIDE);
    for (int fo4 = threadIdx.x; fo4 < RSF4; fo4 += 256) {
        int lo = fo4 * 4 - shift;
        f4 o;
        if (lo >= 0 && lo + 4 <= 3 * MDIM) {
            f4 x;
            ld16(&x, src + lo);
            o.x = ex2(x.x * IV); o.y = ex2(x.y * IV);
            o.z = ex2(x.z * IV); o.w = ex2(x.w * IV);
        } else {
            o.x = ((unsigned)lo       < (unsigned)(3 * MDIM)) ? ex2(src[lo]     * IV) : 0.f;
            o.y = ((unsigned)(lo + 1) < (unsigned)(3 * MDIM)) ? ex2(src[lo + 1] * IV) : 0.f;
            o.z = ((unsigned)(lo + 2) < (unsigned)(3 * MDIM)) ? ex2(src[lo + 2] * IV) : 0.f;
            o.w = ((unsigned)(lo + 3) < (unsigned)(3 * MDIM)) ? ex2(src[lo + 3] * IV) : 0.f;
        }
        dst[fo4] = o;
    }
}

template<int PRE>
__global__ __launch_bounds__(4 * LANES, 1)
__attribute__((amdgpu_waves_per_eu(1, 1)))
void fwd_hmm(const float* __restrict__ theta, const float* __restrict__ A,
             float* __restrict__ out, ull* __restrict__ chunks)
{
    __shared__ ull inRing[RING][18];
    __shared__ ull midRing[RING][18];
    __shared__ ull outRing[RING][18];
    __shared__ int inTag[RING];
    __shared__ int midTag[RING];
    __shared__ int outTag[RING];
    __shared__ int consW;
    __shared__ int midConsW;
    __shared__ int pushedW;

    const int b = blockIdx.x;
    const int tid = threadIdx.x;
    const int wv = tid >> 6;
    const int r = tid & 63;
    const bool bNot0 = (b != 0);

    if (tid == 0) {
        for (int i = 0; i < RING; ++i) { inTag[i] = 0; midTag[i] = 0; outTag[i] = 0; }
        consW = -1; midConsW = -1; pushedW = 0;
    }
    __syncthreads();

    if (wv == 2) {
        // ------ IN transporter: 3 slot-groups x 18 atoms; expands bf16->raw ------
        const int lane = r;
        const int g = lane / 18, q = lane - 18 * g;
        const bool crew = (lane < 54);
        const ull* up = chunks + (size_t)(bNot0 ? b - 1 : 0) * BOUND_ULL;
        int sIn = bNot0 ? 0 : NSLOTS;
        while (sIn < NSLOTS) {
            ull v = 0;
            int eIn = sIn + g;
            bool act = crew & (eIn < NSLOTS);
            if (act) v = ald(up + (size_t)eIn * SLOT_ULL + q);
            int cons = __hip_atomic_load(&consW, __ATOMIC_RELAXED, WGSCOPE);
            bool ok = false;
            if (act) {
                ok = (hi_i(v) == eIn + 1) | ((eIn == 0) & (q < 15));
                ok &= (eIn - cons) <= (RING - 1);
            }
            ull bal = __ballot(ok);
            int n = 0;
            while (n < 3 && ((bal >> (18 * n)) & 0x3FFFFull) == 0x3FFFFull) n++;
            if (n > 0) {
                ull vs = (q < 16) ? pkraw(bflo(v), bfhi(v)) : v;
                if ((g < n) & crew) inRing[eIn & (RING - 1)][q] = vs;
                if (lane == 0)
                    for (int k = 0; k < n; ++k)
                        __hip_atomic_store(&inTag[(sIn + k) & (RING - 1)],
                                           sIn + k + 1, __ATOMIC_RELEASE, WGSCOPE);
                sIn += n;
            } else __builtin_amdgcn_s_sleep(1);
        }
        return;
    }
    if (wv == 3) {
        // ------ OUT transporter: compresses raw->bf16 (+tags) on egress ------
        const int lane = r;
        const int g = lane / 18, q = lane - 18 * g;
        const bool crew = (lane < 54);
        ull* down = chunks + (size_t)(b < NBOUND ? b : 0) * BOUND_ULL;
        int sOut = (b != BANDS - 1) ? 0 : NSLOTS;
        while (sOut < NSLOTS) {
            int eO = sOut + g;
            bool rdy = false;
            if (crew & (eO < NSLOTS))
                rdy = (__hip_atomic_load(&outTag[eO & (RING - 1)],
                                         __ATOMIC_ACQUIRE, WGSCOPE) == eO + 1);
            ull bal = __ballot(rdy);
            int n = 0;
            while (n < 3 && ((bal >> (18 * n)) & 0x3FFFFull) == 0x3FFFFull) n++;
            if (n > 0) {
                if ((g < n) & crew) {
                    ull v = outRing[eO & (RING - 1)][q];
                    ull vs = (q < 16) ? pk2(lo_f(v), hi_f(v), eO + 1)
                                      : pk(lo_f(v), eO + 1);
                    ast(down + (size_t)eO * SLOT_ULL + q, vs);
                }
                sOut += n;
                if (lane == 0)
                    __hip_atomic_store(&pushedW, sOut, __ATOMIC_RELAXED, WGSCOPE);
            } else __builtin_amdgcn_s_sleep(1);
        }
        return;
    }

    // ---------------- unified compute waves (wv 0,1), 64 rows each ----------------
    __builtin_amdgcn_s_setprio(1);   // favor compute over spin-polling transporters
    const float INVLN2 = 1.44269504088896340736f;
    const float LN2    = 0.69314718055994530942f;
    const bool isC = (r == 0);

    float a00 = rf(expf(A[0])), a01 = rf(expf(A[1])), a02 = rf(expf(A[2]));
    float a10 = rf(expf(A[3])), a11 = rf(expf(A[4])), a12 = rf(expf(A[5]));
    float a20 = rf(expf(A[6])), a21 = rf(expf(A[7])), a22 = rf(expf(A[8]));

    float v0 = 0.f, v1 = 0.f, v2 = 0.f;
    float dM = 0.f, dI = 0.f;
    float B = 0.f, Bup = 0.f;
    float dA = 0.f, dB = 0.f, dC = 0.f, dNewC = 0.f;
    float dA2 = 0.f, dB2 = 0.f, dC2 = 0.f;
    float XP = 1.f, XQ = 1.f, XS = 1.f, XP2 = 1.f, XQ2 = 1.f, XS2 = 1.f;
    float carM = 0.f, carI = 0.f;
    int gateCache = 0;
    ull L[18] = {};
    f4 TH0[12], TH1[12];

    // wave-role parameterization (one shared code path)
    ull (*ringIn)[18]  = (wv == 0) ? inRing  : midRing;
    ull (*ringOut)[18] = (wv == 0) ? midRing : outRing;
    int* tagIn   = (wv == 0) ? inTag  : midTag;
    int* tagOut  = (wv == 0) ? midTag : outTag;
    int* consIn  = (wv == 0) ? &consW    : &midConsW;
    int* gateDn  = (wv == 0) ? &midConsW : &pushedW;
    const bool hasIn = (wv == 1) || bNot0;

    const int row = b * 128 + 64 * wv + r;
    const int thRowBase = row * ((PRE != 0) ? RSTRIDE : (3 * MDIM));
    const bool isP = (r == LANES - 1) && ((wv == 0) || (b != BANDS - 1));
    float prevM = (b == 0 && wv == 0 && r == 0) ? (a00 + a01 + a02) : 0.f;

    // prologue: issue batch 0 (retired by window 0's VMWAIT)
    if constexpr (PRE != 0) { ISSUE_P(TH0, 0) } else { THLOAD_C(TH0, 0) }

    float biasD = 0.f;
    if (hasIn && r == 0) {
        while (__hip_atomic_load(&tagIn[0], __ATOMIC_ACQUIRE, WGSCOPE) != 1) {}
        ull c15 = ringIn[0][15], c17 = ringIn[0][17];
        carM = lo_f(c15); carI = hi_f(c15);
        biasD = fminf(lo_f(c17), 100.f);
        __hip_atomic_store(consIn, 0, __ATOMIC_RELAXED, WGSCOPE);
    }
    dA = isC ? biasD : 0.f;
    dB = dA;
    if constexpr (PRE == 0) { KEEPQ(TH0); }

    int w = 0;
    int j = 1 - r;
    // head M windows 0..3
    for (int it = 0; it < 2; ++it) { WIN_M(TH0, TH1) WIN_M(TH1, TH0) }
    // F windows 4..123
    for (int it = 0; it < 60; ++it) { WIN_F(TH0, TH1) WIN_F(TH1, TH0) }
    // tail M windows 124..131
    j = 16 * 124 + 1 - r;
    for (int it = 0; it < 4; ++it) { WIN_M(TH0, TH1) WIN_M(TH1, TH0) }

    // entry 128 atom 15 (col 2049) never produced: dummy + tag commit
    if (isP) {
        ringOut[128 & (RING - 1)][15] = pkraw(0.f, 0.f);
        LGKM0();
        __hip_atomic_store(&tagOut[128 & (RING - 1)], 129, __ATOMIC_RELAXED, WGSCOPE);
    }

    if (wv == 1 && b == BANDS - 1 && r == LANES - 1) {
        out[0] = (B + lg2(v0 + v1 + v2)) * LN2;   // Vt, invariant under rescales
    }
}

extern "C" void kernel_launch(void* const* d_in, const int* in_sizes, int n_in,
                              void* d_out, int out_size, void* d_ws, size_t ws_size,
                              hipStream_t stream) {
    (void)in_sizes; (void)n_in; (void)out_size;
    const float* theta = (const float*)d_in[0];
    const float* A     = (const float*)d_in[1];
    float* out = (float*)d_out;
    ull* chunks = (ull*)d_ws;    // [15 boundaries][129 slots][18 x 8B atoms]
    size_t chunkB = (size_t)NBOUND * BOUND_ULL * sizeof(ull);
    hipMemsetAsync(chunks, 0, chunkB, stream);
    size_t eoff = (chunkB + 255) & ~(size_t)255;
    // +2 padding rows so the tail prefetch (batch up to 132) stays in bounds
    size_t need = eoff + (size_t)(NDIM + 2) * RSTRIDE * sizeof(float);
    if (ws_size >= need) {
        float* E = (float*)((char*)d_ws + eoff);
        hipLaunchKernelGGL(exp_pre, dim3(NDIM), dim3(256), 0, stream, theta, E);
        hipLaunchKernelGGL((fwd_hmm<1>), dim3(BANDS), dim3(4 * LANES), 0, stream,
                           E, A, out, chunks);
    } else {
        hipLaunchKernelGGL((fwd_hmm<0>), dim3(BANDS), dim3(4 * LANES), 0, stream,
                           theta, A, out, chunks);
    }
}